// Round 2
// baseline (305.134 us; speedup 1.0000x reference)
//
#include <hip/hip_runtime.h>
#include <math.h>

#define NBb 16
#define NTt 50
#define NAa 5
#define NHh 128
#define NWw 128
#define NCc 20
#define NCH 26                       // 6 + NC channels
#define NCELL (NBb*NAa*NHh*NWw)      // 1,310,720 cells
#define NFLAT (NCELL*NCH)            // 34,078,720 floats
#define NQ4   (NFLAT/4)              // 8,519,680 float4s (exact)
#define NREC  (NBb*NTt)              // 800 records
#define SCALE_F 16.0f
#define IGNORE_THRES_F 0.5f
#define BAD_CONF_WEIGHT_F 1.25f
#define PI_F 3.14159265358979323846f

// ws layout (float units):
//  [0]  acc_all   (softplus over ALL cells)
//  [2]  acc_obj  [3..7] acc x,y,w,h,r  [8] acc_cls  [9] cnt_mask
//  [10] acc_sub  (softplus over status!=0 cells)   [11] cnt_nonbg
//  [16 .. 16+NCELL)            status grid (uint32): 0=bg, 1=ignored, 2+rec=masked
//  [16+NCELL .. )              records: tx,ty,tw,th,tr (float[800] each), tlab (int[800])
#define STATUS_OFF_F 16
#define REC_OFF_F (16 + NCELL)

__device__ __forceinline__ float inv_tanh_f(float y) {
  if (y <= -1.0f) return -2.0f;
  if (y >= 1.0f)  return  2.0f;
  float ys = fminf(fmaxf(y, -1.0f + 1e-6f), 1.0f - 1e-6f);
  return 0.5f * logf((1.0f + ys) / (1.0f - ys));
}

// softplus(z) = max(z,0) + log1p(exp(-|z|))  == BCE(z, target=0)
__device__ __forceinline__ float softplus_f(float z) {
  return fmaxf(z, 0.0f) + log1pf(expf(-fabsf(z)));
}

__global__ void k_prep(const float* __restrict__ tgt,
                       const int* __restrict__ tsz,
                       const float* __restrict__ anch,
                       float* __restrict__ ws) {
  int tid = blockIdx.x * blockDim.x + threadIdx.x;
  if (tid >= NREC) return;
  int b = tid / NTt, t = tid % NTt;

  float aw[NAa], ah[NAa], ar[NAa], ahw[NAa], ap[NAa][8];
  for (int a = 0; a < NAa; ++a) {
    aw[a] = anch[a*3+0] / SCALE_F;
    ah[a] = anch[a*3+1] / SCALE_F;
    ar[a] = anch[a*3+2];
    float cr = cosf(ar[a]), sr = sinf(ar[a]);
    ap[a][0] = -cr*aw[a]; ap[a][1] =  sr*aw[a];
    ap[a][2] =  cr*aw[a]; ap[a][3] = -sr*aw[a];
    ap[a][4] = -sr*ah[a]; ap[a][5] = -cr*ah[a];
    ap[a][6] =  sr*ah[a]; ap[a][7] =  cr*ah[a];
    ahw[a] = (ah[a] + aw[a]) * 0.5f;
  }

  const float* row = tgt + (size_t)tid * (13 + NCc);
  float gx = row[0] / SCALE_F;
  float gy = row[1] / SCALE_F;
  float gr = row[2];
  float gh = row[3] / SCALE_F;
  float gw = row[4] / SCALE_F;
  bool valid = (t < tsz[b]) && (gw != 0.0f) && (gh != 0.0f);
  if (!valid) return;

  int gi = (int)gx; gi = min(max(gi, 0), NWw - 1);
  int gj = (int)gy; gj = min(max(gj, 0), NHh - 1);

  float cp[8];
  for (int k = 0; k < 8; ++k)
    cp[k] = row[5 + k] / SCALE_F - ((k & 1) ? gy : gx);

  float bestd = 1e30f; int best = 0; unsigned ignm = 0;
  for (int a = 0; a < NAa; ++a) {
    float dn = 0.0f;
    for (int p = 0; p < 8; p += 2) {
      float dx = cp[p]   - ap[a][p];
      float dy = cp[p+1] - ap[a][p+1];
      dn += sqrtf(dx*dx + dy*dy);
    }
    float nm = ((gh + gw) * 0.5f + ahw[a]) * 0.5f;
    float d = dn / nm; d = d * d;
    if (d < IGNORE_THRES_F) ignm |= (1u << a);
    if (d < bestd) { bestd = d; best = a; }
  }

  unsigned* status = (unsigned*)(ws + STATUS_OFF_F);
  int cellbase = ((b * NAa) * NHh + gj) * NWw + gi;
  for (int a = 0; a < NAa; ++a)
    if ((ignm >> a) & 1u) atomicMax(&status[cellbase + a * NHh * NWw], 1u);
  atomicMax(&status[cellbase + best * NHh * NWw], 2u + (unsigned)tid);

  float txv = inv_tanh_f(gx - ((float)gi + 0.5f));
  float tyv = inv_tanh_f(gy - ((float)gj + 0.5f));
  float rd = gr - ar[best];
  if (rd > PI_F) rd -= 2.0f * PI_F;
  else if (rd < -PI_F) rd += 2.0f * PI_F;
  float trv = inv_tanh_f(rd / (PI_F * 0.5f));
  float twv = logf(gw / aw[best] + 1e-16f);
  float thv = logf(gh / ah[best] + 1e-16f);
  int tlab = 0; float bm = row[13];
  for (int c = 1; c < NCc; ++c)
    if (row[13 + c] > bm) { bm = row[13 + c]; tlab = c; }

  float* rec = ws + REC_OFF_F;
  rec[0*NREC + tid] = txv;
  rec[1*NREC + tid] = tyv;
  rec[2*NREC + tid] = twv;
  rec[3*NREC + tid] = thv;
  rec[4*NREC + tid] = trv;
  ((int*)rec)[5*NREC + tid] = tlab;
}

// Streaming kernel: sum softplus(conf) over ALL cells via fully-coalesced
// float4 reads of the entire prediction tensor. No status dependence.
__global__ void k_sum(const float4* __restrict__ pred4, float* __restrict__ ws) {
  float acc = 0.0f;
  int stride = gridDim.x * blockDim.x;
  for (int q = blockIdx.x * blockDim.x + threadIdx.x; q < NQ4; q += stride) {
    float4 v = pred4[q];
    int r = (q * 4) % 26;            // channel of component .x
    // conf (channel 0) present iff r in {0,25,24,23} -> component {x,y,z,w}
    if (r == 0)       acc += softplus_f(v.x);
    else if (r == 25) acc += softplus_f(v.y);
    else if (r == 24) acc += softplus_f(v.z);
    else if (r == 23) acc += softplus_f(v.w);
  }
  // block reduce -> one atomic per block
  for (int off = 32; off; off >>= 1) acc += __shfl_down(acc, off, 64);
  __shared__ float s0[8];
  int wid = threadIdx.x >> 6, lane = threadIdx.x & 63;
  if (lane == 0) s0[wid] = acc;
  __syncthreads();
  if (threadIdx.x == 0) {
    float a = 0.0f;
    int nw = blockDim.x >> 6;
    for (int w = 0; w < nw; ++w) a += s0[w];
    atomicAdd(ws + 0, a);
  }
}

// Correction kernel: scan the 5.25 MB status grid; for the <=4800 non-bg
// cells, subtract their softplus from the all-sum and (for masked cells)
// compute the object/regression/class losses.
__global__ void k_fix(const float* __restrict__ pred, float* __restrict__ ws) {
  const unsigned* __restrict__ status = (const unsigned*)(ws + STATUS_OFF_F);
  const float* __restrict__ rec = ws + REC_OFF_F;
  int stride = gridDim.x * blockDim.x;
  for (int i = blockIdx.x * blockDim.x + threadIdx.x; i < NCELL; i += stride) {
    unsigned st = status[i];
    if (st == 0u) continue;
    const float* cell = pred + (size_t)i * NCH;
    float z = cell[0];
    atomicAdd(ws + 10, softplus_f(z));   // remove from bg sum
    atomicAdd(ws + 11, 1.0f);            // non-bg cell count
    if (st >= 2u) {
      int r = (int)(st - 2u);
      float lobj = softplus_f(z) - z;    // BCE(z, target=1)
      float dx = cell[1] - rec[0*NREC + r];
      float dy = cell[2] - rec[1*NREC + r];
      float dr = cell[3] - rec[4*NREC + r];
      float dh = cell[4] - rec[3*NREC + r];
      float dw = cell[5] - rec[2*NREC + r];
      int tlab = ((const int*)rec)[5*NREC + r];
      float m = cell[6];
      for (int c = 1; c < NCc; ++c) m = fmaxf(m, cell[6 + c]);
      float s = 0.0f;
      for (int c = 0; c < NCc; ++c) s += expf(cell[6 + c] - m);
      float nll = (m + logf(s)) - cell[6 + tlab];
      atomicAdd(ws + 2, lobj);
      atomicAdd(ws + 3, dx * dx);
      atomicAdd(ws + 4, dy * dy);
      atomicAdd(ws + 5, dw * dw);
      atomicAdd(ws + 6, dh * dh);
      atomicAdd(ws + 7, dr * dr);
      atomicAdd(ws + 8, nll);
      atomicAdd(ws + 9, 1.0f);
    }
  }
}

__global__ void k_final(const float* __restrict__ ws, float* __restrict__ out) {
  float acc_bg = ws[0] - ws[10];
  float cnt_bg = (float)NCELL - ws[11];
  float acc_obj = ws[2];
  float ax = ws[3], ay = ws[4], aww = ws[5], ahh = ws[6], arr = ws[7], acls = ws[8];
  float cm = ws[9];
  float db = fmaxf(cnt_bg, 1.0f);
  float dm = fmaxf(cm, 1.0f);
  float loss_conf = BAD_CONF_WEIGHT_F * (acc_bg / db) + acc_obj / dm;
  out[0] = (ax + ay + aww + ahh + arr + acls) / dm + loss_conf;
}

extern "C" void kernel_launch(void* const* d_in, const int* in_sizes, int n_in,
                              void* d_out, int out_size, void* d_ws, size_t ws_size,
                              hipStream_t stream) {
  const float* pred = (const float*)d_in[0];   // (16,5,128,128,26)
  const float* tgt  = (const float*)d_in[1];   // (16,50,33)
  const int*   tsz  = (const int*)d_in[2];     // (16,)
  const float* anch = (const float*)d_in[3];   // (5,3)
  float* ws = (float*)d_ws;

  // zero accumulators + status grid (records don't need init)
  hipMemsetAsync(d_ws, 0, (size_t)(STATUS_OFF_F + NCELL) * sizeof(float), stream);
  k_prep<<<4, 256, 0, stream>>>(tgt, tsz, anch, ws);
  k_sum<<<4096, 256, 0, stream>>>((const float4*)pred, ws);
  k_fix<<<2048, 256, 0, stream>>>(pred, ws);
  k_final<<<1, 1, 0, stream>>>(ws, (float*)d_out);
}

// Round 3
// 243.356 us; speedup vs baseline: 1.2539x; 1.2539x over previous
//
#include <hip/hip_runtime.h>
#include <math.h>

#define NBb 16
#define NTt 50
#define NAa 5
#define NHh 128
#define NWw 128
#define NCc 20
#define NCH 26                       // 6 + NC channels
#define NCELL (NBb*NAa*NHh*NWw)      // 1,310,720 cells
#define NFLAT (NCELL*NCH)            // 34,078,720 floats
#define NQ4   (NFLAT/4)              // 8,519,680 float4s (exact)
#define NREC  (NBb*NTt)              // 800 records
#define NLIST (NREC*7)               // max touched-cell list entries (5 ign + 1 mask + slack)
#define SCALE_F 16.0f
#define IGNORE_THRES_F 0.5f
#define BAD_CONF_WEIGHT_F 1.25f
#define PI_F 3.14159265358979323846f

// ws layout (32-bit units):
//  [0]  acc_all (softplus over ALL cells, from k_sum)
//  [15] list counter (uint)
//  [16 .. 16+NCELL)   status grid (uint32): 0=bg, 1=ignored, 2+rec=masked
//  rec: tx,ty,tw,th,tr (float[NREC] each) + tlab (int[NREC])
//  list: touched cell ids (uint[NLIST], may contain duplicates)
#define STATUS_OFF 16
#define REC_OFF  (STATUS_OFF + NCELL)
#define LIST_OFF (REC_OFF + 6*NREC)

__device__ __forceinline__ float inv_tanh_f(float y) {
  if (y <= -1.0f) return -2.0f;
  if (y >= 1.0f)  return  2.0f;
  float ys = fminf(fmaxf(y, -1.0f + 1e-6f), 1.0f - 1e-6f);
  return 0.5f * logf((1.0f + ys) / (1.0f - ys));
}

// softplus(z) = max(z,0) + log1p(exp(-|z|))  == BCE(z, target=0)
__device__ __forceinline__ float softplus_f(float z) {
  return fmaxf(z, 0.0f) + log1pf(expf(-fabsf(z)));
}

// Zero accumulators + list counter + status grid (ws is 0xAA-poisoned each call).
__global__ void k_zero(unsigned* __restrict__ wsu) {
  int stride = gridDim.x * blockDim.x;
  for (int i = blockIdx.x * blockDim.x + threadIdx.x;
       i < STATUS_OFF + NCELL; i += stride)
    wsu[i] = 0u;
}

__global__ void k_prep(const float* __restrict__ tgt,
                       const int* __restrict__ tsz,
                       const float* __restrict__ anch,
                       float* __restrict__ ws) {
  int tid = blockIdx.x * blockDim.x + threadIdx.x;
  if (tid >= NREC) return;
  int b = tid / NTt, t = tid % NTt;

  float aw[NAa], ah[NAa], ar[NAa], ahw[NAa], ap[NAa][8];
  for (int a = 0; a < NAa; ++a) {
    aw[a] = anch[a*3+0] / SCALE_F;
    ah[a] = anch[a*3+1] / SCALE_F;
    ar[a] = anch[a*3+2];
    float cr = cosf(ar[a]), sr = sinf(ar[a]);
    ap[a][0] = -cr*aw[a]; ap[a][1] =  sr*aw[a];
    ap[a][2] =  cr*aw[a]; ap[a][3] = -sr*aw[a];
    ap[a][4] = -sr*ah[a]; ap[a][5] = -cr*ah[a];
    ap[a][6] =  sr*ah[a]; ap[a][7] =  cr*ah[a];
    ahw[a] = (ah[a] + aw[a]) * 0.5f;
  }

  const float* row = tgt + (size_t)tid * (13 + NCc);
  float gx = row[0] / SCALE_F;
  float gy = row[1] / SCALE_F;
  float gr = row[2];
  float gh = row[3] / SCALE_F;
  float gw = row[4] / SCALE_F;
  bool valid = (t < tsz[b]) && (gw != 0.0f) && (gh != 0.0f);
  if (!valid) return;

  int gi = (int)gx; gi = min(max(gi, 0), NWw - 1);
  int gj = (int)gy; gj = min(max(gj, 0), NHh - 1);

  float cp[8];
  for (int k = 0; k < 8; ++k)
    cp[k] = row[5 + k] / SCALE_F - ((k & 1) ? gy : gx);

  float bestd = 1e30f; int best = 0; unsigned ignm = 0;
  for (int a = 0; a < NAa; ++a) {
    float dn = 0.0f;
    for (int p = 0; p < 8; p += 2) {
      float dx = cp[p]   - ap[a][p];
      float dy = cp[p+1] - ap[a][p+1];
      dn += sqrtf(dx*dx + dy*dy);
    }
    float nm = ((gh + gw) * 0.5f + ahw[a]) * 0.5f;
    float d = dn / nm; d = d * d;
    if (d < IGNORE_THRES_F) ignm |= (1u << a);
    if (d < bestd) { bestd = d; best = a; }
  }

  unsigned* wsu = (unsigned*)ws;
  unsigned* status = wsu + STATUS_OFF;
  unsigned* list = wsu + LIST_OFF;
  int cellbase = ((b * NAa) * NHh + gj) * NWw + gi;
  for (int a = 0; a < NAa; ++a)
    if ((ignm >> a) & 1u) {
      int cell = cellbase + a * NHh * NWw;
      atomicMax(&status[cell], 1u);
      unsigned slot = atomicAdd(&wsu[15], 1u);
      list[slot] = (unsigned)cell;
    }
  {
    int cell = cellbase + best * NHh * NWw;
    // mask scatter: 2+rec; atomicMax => mask beats ignore, last target wins
    atomicMax(&status[cell], 2u + (unsigned)tid);
    if (!((ignm >> best) & 1u)) {           // avoid duplicate list entry
      unsigned slot = atomicAdd(&wsu[15], 1u);
      list[slot] = (unsigned)cell;
    }
  }

  float txv = inv_tanh_f(gx - ((float)gi + 0.5f));
  float tyv = inv_tanh_f(gy - ((float)gj + 0.5f));
  float rd = gr - ar[best];
  if (rd > PI_F) rd -= 2.0f * PI_F;
  else if (rd < -PI_F) rd += 2.0f * PI_F;
  float trv = inv_tanh_f(rd / (PI_F * 0.5f));
  float twv = logf(gw / aw[best] + 1e-16f);
  float thv = logf(gh / ah[best] + 1e-16f);
  int tlab = 0; float bm = row[13];
  for (int c = 1; c < NCc; ++c)
    if (row[13 + c] > bm) { bm = row[13 + c]; tlab = c; }

  float* rec = ws + REC_OFF;
  rec[0*NREC + tid] = txv;
  rec[1*NREC + tid] = tyv;
  rec[2*NREC + tid] = twv;
  rec[3*NREC + tid] = thv;
  rec[4*NREC + tid] = trv;
  ((int*)rec)[5*NREC + tid] = tlab;
}

// Streaming kernel: sum softplus(conf) over ALL cells via fully-coalesced
// float4 reads of the whole prediction tensor. conf (channel 0) lands at
// component .x when q%13==0 and .z when q%13==6 (4q mod 26 is always even).
__global__ void k_sum(const float4* __restrict__ pred4, float* __restrict__ ws) {
  float acc = 0.0f;
  int stride = gridDim.x * blockDim.x;
  for (int q = blockIdx.x * blockDim.x + threadIdx.x; q < NQ4; q += stride) {
    float4 v = pred4[q];
    int m13 = q % 13;
    if (m13 == 0)      acc += softplus_f(v.x);
    else if (m13 == 6) acc += softplus_f(v.z);
  }
  for (int off = 32; off; off >>= 1) acc += __shfl_down(acc, off, 64);
  __shared__ float s0[8];
  int wid = threadIdx.x >> 6, lane = threadIdx.x & 63;
  if (lane == 0) s0[wid] = acc;
  __syncthreads();
  if (threadIdx.x == 0) {
    float a = 0.0f;
    int nw = blockDim.x >> 6;
    for (int w = 0; w < nw; ++w) a += s0[w];
    atomicAdd(ws + 0, a);
  }
}

// Single-block finalize: walk compact touched-cell list, claim each cell once
// (atomicExch -> dedup), accumulate corrections + masked losses in-block,
// then combine with acc_all and write the scalar loss.
__global__ void __launch_bounds__(1024) k_fixfin(const float* __restrict__ pred,
                                                 float* __restrict__ ws,
                                                 float* __restrict__ out) {
  unsigned* wsu = (unsigned*)ws;
  unsigned* status = wsu + STATUS_OFF;
  const unsigned* list = wsu + LIST_OFF;
  const float* rec = ws + REC_OFF;
  int nlist = (int)wsu[15];

  float sub = 0.0f, cnb = 0.0f, obj = 0.0f;
  float sx = 0.0f, sy = 0.0f, sw = 0.0f, sh = 0.0f, sr = 0.0f;
  float scls = 0.0f, cm = 0.0f;

  for (int i = threadIdx.x; i < nlist; i += 1024) {
    unsigned cell = list[i];
    unsigned st = atomicExch(&status[cell], 0u);   // claim; dedups duplicates
    if (st == 0u) continue;
    const float* cp = pred + (size_t)cell * NCH;
    float z = cp[0];
    sub += softplus_f(z);
    cnb += 1.0f;
    if (st >= 2u) {
      int r = (int)(st - 2u);
      obj += softplus_f(z) - z;               // BCE(z, target=1)
      float dx = cp[1] - rec[0*NREC + r];
      float dy = cp[2] - rec[1*NREC + r];
      float dr = cp[3] - rec[4*NREC + r];
      float dh = cp[4] - rec[3*NREC + r];
      float dw = cp[5] - rec[2*NREC + r];
      sx += dx*dx; sy += dy*dy; sw += dw*dw; sh += dh*dh; sr += dr*dr;
      int tlab = ((const int*)rec)[5*NREC + r];
      float m = cp[6];
      for (int c = 1; c < NCc; ++c) m = fmaxf(m, cp[6 + c]);
      float s = 0.0f;
      for (int c = 0; c < NCc; ++c) s += expf(cp[6 + c] - m);
      scls += (m + logf(s)) - cp[6 + tlab];
      cm += 1.0f;
    }
  }

  // block reduction: 10 partials, shfl within wave then LDS across 16 waves
  float vals[10] = {sub, cnb, obj, sx, sy, sw, sh, sr, scls, cm};
  __shared__ float red[16][10];
  int wid = threadIdx.x >> 6, lane = threadIdx.x & 63;
  for (int k = 0; k < 10; ++k) {
    float v = vals[k];
    for (int off = 32; off; off >>= 1) v += __shfl_down(v, off, 64);
    if (lane == 0) red[wid][k] = v;
    vals[k] = v;
  }
  __syncthreads();
  if (threadIdx.x == 0) {
    float tot[10];
    for (int k = 0; k < 10; ++k) {
      float v = 0.0f;
      for (int w = 0; w < 16; ++w) v += red[w][k];
      tot[k] = v;
    }
    float acc_bg = ws[0] - tot[0];
    float cnt_bg = (float)NCELL - tot[1];
    float db = fmaxf(cnt_bg, 1.0f);
    float dm = fmaxf(tot[9], 1.0f);
    float loss_conf = BAD_CONF_WEIGHT_F * (acc_bg / db) + tot[2] / dm;
    out[0] = (tot[3] + tot[4] + tot[5] + tot[6] + tot[7] + tot[8]) / dm + loss_conf;
  }
}

extern "C" void kernel_launch(void* const* d_in, const int* in_sizes, int n_in,
                              void* d_out, int out_size, void* d_ws, size_t ws_size,
                              hipStream_t stream) {
  const float* pred = (const float*)d_in[0];   // (16,5,128,128,26)
  const float* tgt  = (const float*)d_in[1];   // (16,50,33)
  const int*   tsz  = (const int*)d_in[2];     // (16,)
  const float* anch = (const float*)d_in[3];   // (5,3)
  float* ws = (float*)d_ws;

  k_zero<<<1280, 256, 0, stream>>>((unsigned*)ws);
  k_prep<<<4, 256, 0, stream>>>(tgt, tsz, anch, ws);
  k_sum<<<4096, 256, 0, stream>>>((const float4*)pred, ws);
  k_fixfin<<<1, 1024, 0, stream>>>(pred, ws, (float*)d_out);
}